// Round 10
// baseline (90.299 us; speedup 1.0000x reference)
//
#include <hip/hip_runtime.h>

#define N_ 256
#define C_ 2048
#define HW_ 49
#define CPB 64
#define NCC 32          // 64-ch chunks (k_gate / k_mul / fallback k_main)
#define NCHUNK_FB 8     // fallback k_poolc chunking

// local-channel base in sx: 70 channels (3 halo low, 64 main, 3 halo high).
// Main chunk starts at 148 (16B-aligned for float4); halo-low at 0, gap at 147.
#define CHB(lc) ((lc) * HW_ + ((lc) >= 3 ? 1 : 0))

// ============================================================================
// MAIN PATH
// ============================================================================

// ---- kernel 1: per-64ch gates (W/H pools + conv + BN + sigmoid) + channel-pool
//      partials. grid (32, N). LDS 27.1 KB -> 6 blocks/CU. No multiply phase.
__global__ __launch_bounds__(256) void k_gate(const float* __restrict__ x,
    const float* __restrict__ cw, const float* __restrict__ cb,
    const float* __restrict__ bnw, const float* __restrict__ bnb,
    const float* __restrict__ bnrm, const float* __restrict__ bnrv,
    float* __restrict__ psum, float* __restrict__ pmax,
    float* __restrict__ gch_g, float* __restrict__ gcw_g) {
  const int cc = blockIdx.x, n = blockIdx.y;
  const int c0 = cc * CPB;
  const int t  = threadIdx.x;

  __shared__ __align__(16) float sx[3432];       // 70ch x 49 (+gap at 147)
  __shared__ __align__(16) float pool_lo[1120];  // [4][70][4]: k=0..3, 16B rows
  __shared__ __align__(16) float pool_hi[1120];  // [4][70][4]: k=4..6 (+pad)
  __shared__ float part_s[HW_][5];
  __shared__ float part_m[HW_][5];
  __shared__ __align__(16) float s_w[112];       // [2][7][8] weights, q-padded

  const int conv = t & 1, i2 = (t >> 1) & 1, cl = t >> 2;
  const int bi = 1 + conv;
  const float cb0 = cb[0];
  const float sc_bn = bnw[bi] * rsqrtf(bnrv[bi] + 1e-5f);
  const float rm_bn = bnrm[bi];
  const float sh_bn = bnb[bi];

  // ---- P0: stage ----
  if (t < 112) {
    int i2w = t / 56, rem = t % 56, p = rem / 8, q = rem % 8;
    s_w[t] = (q < 7) ? cw[i2w * 49 + p * 7 + q] : 0.f;
  }
  for (int i = t; i < 2 * 3 * HW_; i += 256) {   // halo channels first (latency)
    int side = i / 147, off = i % 147;
    int lc = side ? (67 + off / HW_) : (off / HW_);
    int c = c0 - 3 + lc;
    float vv = 0.f;
    if (c >= 0 && c < C_) vv = x[((size_t)n * C_ + c) * HW_ + off % HW_];
    sx[CHB(lc) + off % HW_] = vv;
  }
  const float4* xv = (const float4*)(x + ((size_t)n * C_ + c0) * HW_);
  float4* sxv = (float4*)(sx + 148);
  for (int v = t; v < 784; v += 256) sxv[v] = xv[v];
  __syncthreads();

  // ---- P1: W/H pools for 70 local channels + channel-pool partials ----
  for (int i = t; i < 70 * 7; i += 256) {
    int lc = i / 7, k = i % 7;
    int base = CHB(lc);
    float s1 = 0.f, m1 = -3.4e38f, s2 = 0.f, m2 = -3.4e38f;
    #pragma unroll
    for (int j = 0; j < 7; ++j) {
      float a = sx[base + k * 7 + j]; s1 += a; m1 = fmaxf(m1, a);  // h=k vary w
      float b = sx[base + j * 7 + k]; s2 += b; m2 = fmaxf(m2, b);  // w=k vary h
    }
    float* pb = (k < 4) ? pool_lo : pool_hi;
    int kk = k & 3;
    pb[(0 * 70 + lc) * 4 + kk] = s1 * (1.f / 7.f);  // f0: g_ch mean(W)
    pb[(1 * 70 + lc) * 4 + kk] = m1;                // f1: g_ch max(W)
    pb[(2 * 70 + lc) * 4 + kk] = s2 * (1.f / 7.f);  // f2: g_cw mean(H)
    pb[(3 * 70 + lc) * 4 + kk] = m2;                // f3: g_cw max(H)
  }
  if (t < 245) {                       // channel-pool partials over the 64 main ch
    int hw = t / 5, s = t % 5;
    float sm = 0.f, mx = -3.4e38f;
    #pragma unroll
    for (int j = 0; j < 13; ++j) {
      int c = s * 13 + j;
      if (c < CPB) {
        float a = sx[(c + 3) * HW_ + 1 + hw];   // CHB(c+3)
        sm += a; mx = fmaxf(mx, a);
      }
    }
    part_s[hw][s] = sm; part_m[hw][s] = mx;
  }
  __syncthreads();

  // ---- P2: finalize partials + conv + gate write ----
  if (t < HW_) {
    float sm = 0.f, mx = -3.4e38f;
    #pragma unroll
    for (int k = 0; k < 5; ++k) { sm += part_s[t][k]; mx = fmaxf(mx, part_m[t][k]); }
    size_t o = ((size_t)n * NCC + cc) * HW_ + t;
    psum[o] = sm; pmax[o] = mx;
  }
  {
    const int f = conv * 2 + i2;
    const float* Wb = s_w + i2 * 56;             // 2 distinct addrs/wave: free
    float acc[7] = {0.f, 0.f, 0.f, 0.f, 0.f, 0.f, 0.f};
    #pragma unroll
    for (int p = 0; p < 7; ++p) {
      int ri = (f * 70 + cl + p) * 4;
      float4 r0 = *(const float4*)(pool_lo + ri);
      float4 r1 = *(const float4*)(pool_hi + ri);
      float row[7] = {r0.x, r0.y, r0.z, r0.w, r1.x, r1.y, r1.z};
      float4 w0 = *(const float4*)(Wb + p * 8);
      float4 w1 = *(const float4*)(Wb + p * 8 + 4);
      float wr[7] = {w0.x, w0.y, w0.z, w0.w, w1.x, w1.y, w1.z};
      #pragma unroll
      for (int q = 0; q < 7; ++q)
        #pragma unroll
        for (int k = 0; k < 7; ++k) {
          int c = k + q - 3;                     // compile-time after unroll
          if (c >= 0 && c < 7) acc[k] += row[c] * wr[q];
        }
    }
    float fsum[7];
    #pragma unroll
    for (int k = 0; k < 7; ++k) fsum[k] = acc[k] + __shfl_xor(acc[k], 2, 64);
    if (i2 == 0) {
      float* gp = (conv ? gcw_g : gch_g) + ((size_t)n * C_ + c0 + cl) * 7;
      #pragma unroll
      for (int k = 0; k < 7; ++k) {
        float y = (fsum[k] + cb0 - rm_bn) * sc_bn + sh_bn;
        y = fmaxf(y, 0.f);
        gp[k] = 1.f / (1.f + __expf(-y));
      }
    }
  }
}

// ---- kernel 2: reduce chunk partials, compute g_hw gate per n ----
__global__ __launch_bounds__(64) void k_ghw(const float* __restrict__ psum,
                                            const float* __restrict__ pmax,
                                            const float* __restrict__ cw,
                                            const float* __restrict__ cb,
                                            const float* __restrict__ bnw,
                                            const float* __restrict__ bnb,
                                            const float* __restrict__ bnrm,
                                            const float* __restrict__ bnrv,
                                            float* __restrict__ ghw, int nchunk) {
  const int n = blockIdx.x;
  const int t = threadIdx.x;
  __shared__ float p2c[2][13][13];
  __shared__ float s_cw[98];

  for (int i = t; i < 2 * 13 * 13; i += 64) ((float*)p2c)[i] = 0.f;
  for (int i = t; i < 98; i += 64) s_cw[i] = cw[i];
  __syncthreads();

  if (t < HW_) {
    float sm = 0.f, mx = -3.4e38f;
    const float* ps = psum + (size_t)n * nchunk * HW_ + t;
    const float* pm = pmax + (size_t)n * nchunk * HW_ + t;
    for (int cc = 0; cc < nchunk; ++cc) {
      sm += ps[cc * HW_];
      mx = fmaxf(mx, pm[cc * HW_]);
    }
    p2c[0][t / 7 + 3][t % 7 + 3] = sm * (1.f / C_);
    p2c[1][t / 7 + 3][t % 7 + 3] = mx;
  }
  __syncthreads();

  if (t < HW_) {
    int a = t / 7, b = t % 7;
    float y = cb[0];
    #pragma unroll
    for (int i2 = 0; i2 < 2; ++i2)
      #pragma unroll
      for (int p = 0; p < 7; ++p)
        #pragma unroll
        for (int q = 0; q < 7; ++q)
          y += p2c[i2][a + p][b + q] * s_cw[i2 * 49 + p * 7 + q];
    float sc = bnw[0] * rsqrtf(bnrv[0] + 1e-5f);
    y = (y - bnrm[0]) * sc + bnb[0];
    y = fmaxf(y, 0.f);
    ghw[n * HW_ + t] = 1.f / (1.f + __expf(-y));
  }
}

// ---- kernel 3: pure streaming fused multiply (measured ~13-14 us in r9) ----
__global__ __launch_bounds__(256) void k_mul(const float* __restrict__ x,
    const float* __restrict__ ghw, const float* __restrict__ gch_g,
    const float* __restrict__ gcw_g, float* __restrict__ out) {
  const int cc = blockIdx.x;
  const int n  = (N_ - 1) - blockIdx.y;   // reverse n: read freshest L3 lines first
  const int c0 = cc * CPB;
  const int t  = threadIdx.x;

  __shared__ float sg[960];  // [0,448) gch, [448,896) gcw, [896,945) ghw

  {
    const float* g1 = gch_g + ((size_t)n * C_ + c0) * 7;
    const float* g2 = gcw_g + ((size_t)n * C_ + c0) * 7;
    for (int i = t; i < 945; i += 256) {
      float v;
      if (i < 448)      v = g1[i];
      else if (i < 896) v = g2[i - 448];
      else              v = ghw[n * HW_ + (i - 896)];
      sg[i] = v;
    }
  }
  __syncthreads();
  const float* gch = sg;
  const float* gcw = sg + 448;
  const float* s_ghw = sg + 896;

  const float4* xv = (const float4*)(x + ((size_t)n * C_ + c0) * HW_);
  float4* outv = (float4*)(out + ((size_t)n * C_ + c0) * HW_);
  for (int v = t; v < 784; v += 256) {
    float4 q = xv[v];
    int e0 = v * 4;
    int cj = e0 / 49;
    int hw0 = e0 - cj * 49;
    float r[4] = {q.x, q.y, q.z, q.w};
    #pragma unroll
    for (int j = 0; j < 4; ++j) {
      int hw = hw0 + j;
      int cjj = cj + (hw >= 49);
      hw -= (hw >= 49) ? 49 : 0;
      int h = (hw * 37) >> 8, w2 = hw - h * 7;
      r[j] *= (s_ghw[hw] + gch[cjj * 7 + h] + gcw[cjj * 7 + w2]) * (1.f / 3.f);
    }
    outv[v] = make_float4(r[0], r[1], r[2], r[3]);
  }
}

// ============================================================================
// FALLBACK PATH (round-8 kernels) — only if ws is too small for gates
// ============================================================================

__global__ __launch_bounds__(256) void k_poolc_fb(const float* __restrict__ x,
                                                  float* __restrict__ psum,
                                                  float* __restrict__ pmax) {
  const int bc = blockIdx.x, n = blockIdx.y;
  const int t = threadIdx.x;
  __shared__ __align__(16) float sx[CPB * HW_];
  __shared__ float part_s[HW_][5];
  __shared__ float part_m[HW_][5];

  float sm = 0.f, mx = -3.4e38f;
  const int hw = t / 5, s = t % 5;

  const float4* xv = (const float4*)(x + ((size_t)n * C_ + (size_t)bc * 256) * HW_);
  #pragma unroll
  for (int pass = 0; pass < 4; ++pass) {
    float4* sv = (float4*)sx;
    for (int v = t; v < 784; v += 256) sv[v] = xv[pass * 784 + v];
    __syncthreads();
    if (t < 245) {
      #pragma unroll
      for (int j = 0; j < 13; ++j) {
        int c = s * 13 + j;
        if (c < CPB) { float a = sx[c * HW_ + hw]; sm += a; mx = fmaxf(mx, a); }
      }
    }
    __syncthreads();
  }
  if (t < 245) { part_s[hw][s] = sm; part_m[hw][s] = mx; }
  __syncthreads();
  if (t < HW_) {
    float s2 = 0.f, m2 = -3.4e38f;
    #pragma unroll
    for (int k = 0; k < 5; ++k) { s2 += part_s[t][k]; m2 = fmaxf(m2, part_m[t][k]); }
    size_t o = ((size_t)n * NCHUNK_FB + bc) * HW_ + t;
    psum[o] = s2; pmax[o] = m2;
  }
}

__global__ __launch_bounds__(256, 6) void k_main_fb(const float* __restrict__ x,
    const float* __restrict__ ghw,
    const float* __restrict__ cw, const float* __restrict__ cb,
    const float* __restrict__ bnw, const float* __restrict__ bnb,
    const float* __restrict__ bnrm, const float* __restrict__ bnrv,
    float* __restrict__ out) {
  const int cc = blockIdx.x;
  const int n  = (N_ - 1) - blockIdx.y;
  const int c0 = cc * CPB;
  const int t  = threadIdx.x;

  __shared__ __align__(16) float sx[3432];
  __shared__ __align__(16) float pool_lo[1120];
  __shared__ __align__(16) float pool_hi[1120];
  __shared__ float gch[448];
  __shared__ float gcw[448];
  __shared__ __align__(16) float s_w[112];
  __shared__ float s_ghw[49];

  const int conv = t & 1, i2 = (t >> 1) & 1, cl = t >> 2;
  const int bi = 1 + conv;
  const float cb0 = cb[0];
  const float sc_bn = bnw[bi] * rsqrtf(bnrv[bi] + 1e-5f);
  const float rm_bn = bnrm[bi];
  const float sh_bn = bnb[bi];

  if (t < 112) {
    int i2w = t / 56, rem = t % 56, p = rem / 8, q = rem % 8;
    s_w[t] = (q < 7) ? cw[i2w * 49 + p * 7 + q] : 0.f;
  }
  if (t < HW_) s_ghw[t] = ghw[n * HW_ + t];
  for (int i = t; i < 2 * 3 * HW_; i += 256) {
    int side = i / 147, off = i % 147;
    int lc = side ? (67 + off / HW_) : (off / HW_);
    int c = c0 - 3 + lc;
    float vv = 0.f;
    if (c >= 0 && c < C_) vv = x[((size_t)n * C_ + c) * HW_ + off % HW_];
    sx[CHB(lc) + off % HW_] = vv;
  }
  const float4* xv = (const float4*)(x + ((size_t)n * C_ + c0) * HW_);
  float4* sxv = (float4*)(sx + 148);
  for (int v = t; v < 784; v += 256) sxv[v] = xv[v];
  __syncthreads();

  for (int i = t; i < 70 * 7; i += 256) {
    int lc = i / 7, k = i % 7;
    int base = CHB(lc);
    float s1 = 0.f, m1 = -3.4e38f, s2 = 0.f, m2 = -3.4e38f;
    #pragma unroll
    for (int j = 0; j < 7; ++j) {
      float a = sx[base + k * 7 + j]; s1 += a; m1 = fmaxf(m1, a);
      float b = sx[base + j * 7 + k]; s2 += b; m2 = fmaxf(m2, b);
    }
    float* pb = (k < 4) ? pool_lo : pool_hi;
    int kk = k & 3;
    pb[(0 * 70 + lc) * 4 + kk] = s1 * (1.f / 7.f);
    pb[(1 * 70 + lc) * 4 + kk] = m1;
    pb[(2 * 70 + lc) * 4 + kk] = s2 * (1.f / 7.f);
    pb[(3 * 70 + lc) * 4 + kk] = m2;
  }
  __syncthreads();

  {
    const int f = conv * 2 + i2;
    const float* Wb = s_w + i2 * 56;
    float acc[7] = {0.f, 0.f, 0.f, 0.f, 0.f, 0.f, 0.f};
    #pragma unroll
    for (int p = 0; p < 7; ++p) {
      int ri = (f * 70 + cl + p) * 4;
      float4 r0 = *(const float4*)(pool_lo + ri);
      float4 r1 = *(const float4*)(pool_hi + ri);
      float row[7] = {r0.x, r0.y, r0.z, r0.w, r1.x, r1.y, r1.z};
      float4 w0 = *(const float4*)(Wb + p * 8);
      float4 w1 = *(const float4*)(Wb + p * 8 + 4);
      float wr[7] = {w0.x, w0.y, w0.z, w0.w, w1.x, w1.y, w1.z};
      #pragma unroll
      for (int q = 0; q < 7; ++q)
        #pragma unroll
        for (int k = 0; k < 7; ++k) {
          int c = k + q - 3;
          if (c >= 0 && c < 7) acc[k] += row[c] * wr[q];
        }
    }
    float fsum[7];
    #pragma unroll
    for (int k = 0; k < 7; ++k) fsum[k] = acc[k] + __shfl_xor(acc[k], 2, 64);
    if (i2 == 0) {
      float* gp = (conv ? gcw : gch) + cl * 7;
      #pragma unroll
      for (int k = 0; k < 7; ++k) {
        float y = (fsum[k] + cb0 - rm_bn) * sc_bn + sh_bn;
        y = fmaxf(y, 0.f);
        gp[k] = 1.f / (1.f + __expf(-y));
      }
    }
  }
  __syncthreads();

  float4* outv = (float4*)(out + ((size_t)n * C_ + c0) * HW_);
  for (int v = t; v < 784; v += 256) {
    float4 q = sxv[v];
    int e0 = v * 4;
    int cj = e0 / 49;
    int hw0 = e0 - cj * 49;
    float r[4] = {q.x, q.y, q.z, q.w};
    #pragma unroll
    for (int j = 0; j < 4; ++j) {
      int hw = hw0 + j;
      int cjj = cj + (hw >= 49);
      hw -= (hw >= 49) ? 49 : 0;
      int h = (hw * 37) >> 8, w2 = hw - h * 7;
      r[j] *= (s_ghw[hw] + gch[cjj * 7 + h] + gcw[cjj * 7 + w2]) * (1.f / 3.f);
    }
    outv[v] = make_float4(r[0], r[1], r[2], r[3]);
  }
}

extern "C" void kernel_launch(void* const* d_in, const int* in_sizes, int n_in,
                              void* d_out, int out_size, void* d_ws, size_t ws_size,
                              hipStream_t stream) {
  const float* x    = (const float*)d_in[0];
  const float* cw   = (const float*)d_in[1];
  const float* cb   = (const float*)d_in[2];
  const float* bnw  = (const float*)d_in[3];
  const float* bnb  = (const float*)d_in[4];
  const float* bnrm = (const float*)d_in[5];
  const float* bnrv = (const float*)d_in[6];
  float* out = (float*)d_out;

  float* psum  = (float*)d_ws;                          // N*32*49
  float* pmax  = psum + (size_t)N_ * NCC * HW_;         // N*32*49
  float* ghw   = pmax + (size_t)N_ * NCC * HW_;         // N*49
  float* gch_g = ghw + (size_t)N_ * HW_;                // N*C*7
  float* gcw_g = gch_g + (size_t)N_ * C_ * 7;           // N*C*7
  size_t need_floats = (size_t)N_ * NCC * HW_ * 2 + (size_t)N_ * HW_
                     + (size_t)N_ * C_ * 7 * 2;

  if (ws_size >= need_floats * sizeof(float)) {
    k_gate<<<dim3(NCC, N_), 256, 0, stream>>>(
        x, cw, cb, bnw, bnb, bnrm, bnrv, psum, pmax, gch_g, gcw_g);
    k_ghw<<<dim3(N_), 64, 0, stream>>>(psum, pmax, cw, cb, bnw, bnb, bnrm, bnrv,
                                       ghw, NCC);
    k_mul<<<dim3(NCC, N_), 256, 0, stream>>>(x, ghw, gch_g, gcw_g, out);
  } else {
    k_poolc_fb<<<dim3(NCHUNK_FB, N_), 256, 0, stream>>>(x, psum, pmax);
    k_ghw<<<dim3(N_), 64, 0, stream>>>(psum, pmax, cw, cb, bnw, bnb, bnrm, bnrv,
                                       ghw, NCHUNK_FB);
    k_main_fb<<<dim3(NCC, N_), 256, 0, stream>>>(x, ghw, cw, cb, bnw, bnb, bnrm,
                                                 bnrv, out);
  }
}